// Round 12
// baseline (293.364 us; speedup 1.0000x reference)
//
#include <hip/hip_runtime.h>

// Problem dims (fixed by setup_inputs)
#define Bb 8
#define Tt 2048
#define Hh 1024
#define Kk 256
#define Vv 256
#define Oo 1024
#define CC 64   // chunk length
#define NC 32   // chunks per batch (Tt/CC)

typedef __attribute__((ext_vector_type(8))) __bf16 bf16x8;
typedef __attribute__((ext_vector_type(4))) float f32x4;

__device__ __forceinline__ unsigned short f2b(float f) {
  unsigned u = __float_as_uint(f);
  u = (u + 0x7FFFu + ((u >> 16) & 1u)) >> 16;
  return (unsigned short)u;
}
__device__ __forceinline__ float b2f(unsigned short u) {
  return __uint_as_float(((unsigned)u) << 16);
}
__device__ __forceinline__ void gload_lds16(const unsigned short* g, unsigned short* l) {
  __builtin_amdgcn_global_load_lds(
      (const __attribute__((address_space(1))) void*)g,
      (__attribute__((address_space(3))) void*)l, 16, 0, 0);
}

// ---------------- cast f32 -> bf16 (vectorized) ----------------
__global__ __launch_bounds__(256) void cast_bf16_kernel(const float* __restrict__ in,
                                                        unsigned short* __restrict__ out,
                                                        int n4) {
  int i = blockIdx.x * 256 + threadIdx.x;
  if (i >= n4) return;
  float4 v = ((const float4*)in)[i];
  ushort4 o;
  o.x = f2b(v.x); o.y = f2b(v.y); o.z = f2b(v.z); o.w = f2b(v.w);
  ((ushort4*)out)[i] = o;
}

// ---------------- transpose + cast: W (H x N) f32 -> WT (N x H) bf16 ----------------
__global__ __launch_bounds__(256) void transpose_cast_kernel(const float* __restrict__ W,
                                                             unsigned short* __restrict__ WT,
                                                             int H, int N) {
  __shared__ float tile[32][33];
  int h0 = blockIdx.x * 32, n0 = blockIdx.y * 32;
  int tx = threadIdx.x & 31, ty = threadIdx.x >> 5;
  for (int r = ty; r < 32; r += 8)
    tile[r][tx] = W[(size_t)(h0 + r) * N + n0 + tx];
  __syncthreads();
  for (int r = ty; r < 32; r += 8)
    WT[(size_t)(n0 + r) * H + h0 + tx] = f2b(tile[tx][r]);
}

// ---------------- proj GEMM: 128x128 tiles, persistent 2-m-tile blocks ----------------
// grid = 512 blocks (2/CU). Each block: same n-panel, two m-tiles sequentially.
// Concurrent working set per XCD: 8 A-panels (2MB) + B (2MB) = 4MB -> fits L2.
// Epilogue: LDS-staged coalesced writes; v-panel written transposed to vT.
#define BM 128
#define BN 128
#define BK 64

__global__ __launch_bounds__(256, 4) void gemm_proj_kernel(
    const unsigned short* __restrict__ A, const unsigned short* __restrict__ Bt,
    const float* __restrict__ b0p, const float* __restrict__ b1p,
    const float* __restrict__ b2p, const float* __restrict__ b3p,
    unsigned short* __restrict__ O0, unsigned short* __restrict__ O1,
    unsigned short* __restrict__ O2, unsigned short* __restrict__ O3,
    int K) {
  __shared__ __align__(16) unsigned short shbuf[16384];  // 32 KiB: As/Bs, then epilogue
  unsigned short* As = shbuf;
  unsigned short* Bs = shbuf + 8192;
  const int tid = threadIdx.x;
  const int lane = tid & 63, wid = tid >> 6;
  const int wm = wid >> 1, wn = wid & 1;
  // XCD owns m-panels [xcd*16, xcd*16+16); half h covers 8 of them.
  const int lin = blockIdx.x;            // 512 blocks; lin&7 = XCD (hw round-robin)
  const int xcd = lin & 7;
  const int rem = lin >> 3;              // 0..63
  const int jm = rem & 7, jn = rem >> 3; // 8 m-slots x 8 n-panels
  const int n0 = jn * 128;
  const int sel = n0 >> 8;
  const float* bp = sel == 0 ? b0p : sel == 1 ? b1p : sel == 2 ? b2p : b3p;
  const int fr = lane & 15, fq = lane >> 4;
  const int srl = lane >> 3;
  const int scs = ((lane & 7) ^ srl) * 8;
  const int nt = K / BK;

  for (int h = 0; h < 2; ++h) {
    const int m0 = (xcd * 16 + h * 8 + jm) * BM;
    const unsigned short* gaBase = A + (size_t)(m0 + srl) * K + scs;
    const unsigned short* gbBase = Bt + (size_t)(n0 + srl) * K + scs;
    f32x4 acc[4][4] = {};
    for (int t = 0; t < nt; ++t) {
      const int k0 = t * BK;
      __syncthreads();  // previous LDS users done (incl. prior half's epilogue)
#pragma unroll
      for (int inst = 0; inst < 4; ++inst) {
        const int rb = wid * 32 + inst * 8;
        gload_lds16(gaBase + (size_t)rb * K + k0, &As[rb * BK]);
        gload_lds16(gbBase + (size_t)rb * K + k0, &Bs[rb * BK]);
      }
      __syncthreads();
#pragma unroll
      for (int ks = 0; ks < 2; ++ks) {
        bf16x8 af[4], bfv[4];
#pragma unroll
        for (int j = 0; j < 4; ++j) {
          const int R = wn * 64 + j * 16 + fr;
          const int ch = ((ks << 2) | fq) ^ (fr & 7);
          bfv[j] = *(const bf16x8*)&Bs[R * BK + ch * 8];
        }
#pragma unroll
        for (int i = 0; i < 4; ++i) {
          const int R = wm * 64 + i * 16 + fr;
          const int ch = ((ks << 2) | fq) ^ (fr & 7);
          af[i] = *(const bf16x8*)&As[R * BK + ch * 8];
        }
#pragma unroll
        for (int i = 0; i < 4; ++i)
#pragma unroll
          for (int j = 0; j < 4; ++j)
            acc[i][j] = __builtin_amdgcn_mfma_f32_16x16x32_bf16(af[i], bfv[j], acc[i][j], 0, 0, 0);
      }
    }
    // LDS-staged epilogue (coalesced 256B rows; v-panel staged transposed)
    __syncthreads();
#pragma unroll
    for (int j = 0; j < 4; ++j) {
      const int ncol = wn * 64 + j * 16 + fr;       // [0,128)
      const float bv = bp[(n0 & 255) + ncol];
#pragma unroll
      for (int i = 0; i < 4; ++i) {
#pragma unroll
        for (int r = 0; r < 4; ++r) {
          const int ml = wm * 64 + i * 16 + fq * 4 + r;
          const float x = acc[i][j][r] + bv;
          unsigned short us;
          if (sel == 0) {
            us = f2b(x);
          } else if (sel == 1) {
            us = f2b(1.f / (1.f + expf(-x)));
          } else if (sel == 2) {
            float e = exp2f(-x * 1.44269504f);
            float lg = -log2f(1.f + e);
            _Float16 hv = (_Float16)lg;
            __builtin_memcpy(&us, &hv, 2);
          } else {
            us = f2b(x);
          }
          if (sel == 3) {  // transposed: row=v(ncol), col=t(ml)
            const int cm = (ml >> 3) ^ (ncol & 15);
            shbuf[ncol * 128 + cm * 8 + (ml & 7)] = us;
          } else {
            const int cn = (ncol >> 3) ^ (ml & 15);
            shbuf[ml * 128 + cn * 8 + (ncol & 7)] = us;
          }
        }
      }
    }
    __syncthreads();
    const int row = tid >> 1;
    const int half = tid & 1;
    if (sel == 3) {
      unsigned short* dst = O3 + ((size_t)(m0 >> 11) * Vv + (n0 & 255) + row) * Tt +
                            (m0 & 2047) + half * 64;
#pragma unroll
      for (int ic = 0; ic < 8; ++ic) {
        const int chunk = half * 8 + ic;
        const int sc = chunk ^ (row & 15);
        *(uint4*)(dst + ic * 8) = *(const uint4*)&shbuf[row * 128 + sc * 8];
      }
    } else {
      unsigned short* Op = sel == 0 ? O0 : sel == 1 ? O1 : O2;
      unsigned short* dst = Op + (size_t)(m0 + row) * 256 + (n0 & 255) + half * 64;
#pragma unroll
      for (int ic = 0; ic < 8; ++ic) {
        const int chunk = half * 8 + ic;
        const int sc = chunk ^ (row & 15);
        *(uint4*)(dst + ic * 8) = *(const uint4*)&shbuf[row * 128 + sc * 8];
      }
    }
  }
}

// ---------------- out-proj GEMM: 128x128, LDS-staged f32 writes (full 512B rows) ----
__global__ __launch_bounds__(256, 4) void gemm_out_kernel(
    const unsigned short* __restrict__ A, const unsigned short* __restrict__ Bt,
    const float* __restrict__ bias, float* __restrict__ Cf,
    int M, int N, int K) {
  // One LDS pool: 32KB loop buffers; epilogue reuses as 64x132 f32 stage (33792B)
  __shared__ __align__(16) float fstage[8448];
  unsigned short* As = (unsigned short*)fstage;
  unsigned short* Bs = As + 8192;
  const int tid = threadIdx.x;
  const int lane = tid & 63, wid = tid >> 6;
  const int wm = wid >> 1, wn = wid & 1;
  const int lin = blockIdx.x + blockIdx.y * gridDim.x;
  const int xcd = lin & 7;
  const int jj = lin >> 3;
  const int mpg = gridDim.y >> 3;
  const int m0 = (xcd * mpg + jj / gridDim.x) * BM;
  const int n0 = (jj % gridDim.x) * BN;
  const int fr = lane & 15, fq = lane >> 4;
  const int srl = lane >> 3;
  const int scs = ((lane & 7) ^ srl) * 8;
  const unsigned short* gaBase = A + (size_t)(m0 + srl) * K + scs;
  const unsigned short* gbBase = Bt + (size_t)(n0 + srl) * K + scs;

  f32x4 acc[4][4] = {};
  const int nt = K / BK;
  for (int t = 0; t < nt; ++t) {
    const int k0 = t * BK;
    __syncthreads();
#pragma unroll
    for (int inst = 0; inst < 4; ++inst) {
      const int rb = wid * 32 + inst * 8;
      gload_lds16(gaBase + (size_t)rb * K + k0, &As[rb * BK]);
      gload_lds16(gbBase + (size_t)rb * K + k0, &Bs[rb * BK]);
    }
    __syncthreads();
#pragma unroll
    for (int ks = 0; ks < 2; ++ks) {
      bf16x8 af[4], bfv[4];
#pragma unroll
      for (int j = 0; j < 4; ++j) {
        const int R = wn * 64 + j * 16 + fr;
        const int ch = ((ks << 2) | fq) ^ (fr & 7);
        bfv[j] = *(const bf16x8*)&Bs[R * BK + ch * 8];
      }
#pragma unroll
      for (int i = 0; i < 4; ++i) {
        const int R = wm * 64 + i * 16 + fr;
        const int ch = ((ks << 2) | fq) ^ (fr & 7);
        af[i] = *(const bf16x8*)&As[R * BK + ch * 8];
      }
#pragma unroll
      for (int i = 0; i < 4; ++i)
#pragma unroll
        for (int j = 0; j < 4; ++j)
          acc[i][j] = __builtin_amdgcn_mfma_f32_16x16x32_bf16(af[i], bfv[j], acc[i][j], 0, 0, 0);
    }
  }
  // epilogue: two 64-row chunks staged in LDS (132-f32 padded rows), coalesced out
  for (int ch = 0; ch < 2; ++ch) {
    __syncthreads();  // prior LDS users done
    if (wm == ch) {
#pragma unroll
      for (int j = 0; j < 4; ++j) {
        const int col = wn * 64 + j * 16 + fr;
        const float bv = bias[n0 + col];
#pragma unroll
        for (int i = 0; i < 4; ++i)
#pragma unroll
          for (int r = 0; r < 4; ++r)
            fstage[(i * 16 + fq * 4 + r) * 132 + col] = acc[i][j][r] + bv;
      }
    }
    __syncthreads();
    const int rl = tid >> 2, qc = tid & 3;
    float* dst = Cf + (size_t)(m0 + ch * 64 + rl) * N + n0 + qc * 32;
    const float* src = fstage + rl * 132 + qc * 32;
#pragma unroll
    for (int e = 0; e < 8; ++e)
      *(float4*)(dst + e * 4) = *(const float4*)(src + e * 4);
  }
}

// ---------------- fused prep+sgemm: per (b,c) task ----------------
__global__ __launch_bounds__(256) void prep_sgemm_kernel(
    const unsigned short* __restrict__ qb, const unsigned short* __restrict__ kb,
    const unsigned short* __restrict__ lgb, const unsigned short* __restrict__ vTb,
    unsigned short* __restrict__ q2b, unsigned short* __restrict__ qab,
    unsigned short* __restrict__ kab,
    float* __restrict__ LBb, float* __restrict__ Dendb,
    unsigned short* __restrict__ Sb) {
  __shared__ __align__(16) unsigned short khs[256][72];
  const int c = blockIdx.x, b = blockIdx.y;
  const int k = threadIdx.x;
  const int task = b * NC + c;
  const size_t rowbase = ((size_t)b * Tt + (size_t)c * CC) * Kk + k;
  float Ls = 0.f;
  float LBr[4];
#pragma unroll
  for (int gq = 0; gq < 4; ++gq) {
    LBr[gq] = Ls;
#pragma unroll
    for (int tt = 0; tt < 16; ++tt) {
      int t = gq * 16 + tt;
      _Float16 hv;
      __builtin_memcpy(&hv, &lgb[rowbase + (size_t)t * Kk], 2);
      Ls += (float)hv;
    }
  }
  const float Lend = Ls;
#pragma unroll
  for (int gq = 0; gq < 4; ++gq) LBb[(size_t)task * 1024 + gq * 256 + k] = LBr[gq];
  Dendb[task * 256 + k] = exp2f(Lend);
  float L = 0.f;
#pragma unroll
  for (int gq = 0; gq < 4; ++gq) {
    const float LBc = LBr[gq];
    unsigned kw[8];
#pragma unroll
    for (int tt = 0; tt < 16; ++tt) {
      int t = gq * 16 + tt;
      size_t off = rowbase + (size_t)t * Kk;
      _Float16 hv;
      __builtin_memcpy(&hv, &lgb[off], 2);
      L += (float)hv;
      float qv = b2f(qb[off]);
      float kv = b2f(kb[off]);
      q2b[off] = f2b(qv * exp2f(L));
      qab[off] = f2b(qv * exp2f(L - LBc));
      kab[off] = f2b(kv * exp2f(LBc - L));
      unsigned short kh = f2b(kv * exp2f(Lend - L));
      if (tt & 1) kw[tt >> 1] |= ((unsigned)kh) << 16;
      else        kw[tt >> 1] = kh;
    }
    uint4 u0; u0.x = kw[0]; u0.y = kw[1]; u0.z = kw[2]; u0.w = kw[3];
    uint4 u1; u1.x = kw[4]; u1.y = kw[5]; u1.z = kw[6]; u1.w = kw[7];
    *(uint4*)&khs[k][gq * 16] = u0;
    *(uint4*)&khs[k][gq * 16 + 8] = u1;
  }
  __syncthreads();
  const int tid = threadIdx.x, lane = tid & 63, w = tid >> 6;
  const int fr = lane & 15, fq = lane >> 4, fk = fq * 8;
  const unsigned short* vt = vTb + (size_t)b * (Vv * Tt) + (size_t)c * CC;
  for (int vb4 = 0; vb4 < 4; ++vb4) {
    f32x4 acc[4][4] = {};
#pragma unroll
    for (int ks = 0; ks < 2; ++ks) {
      bf16x8 af[4], bf[4];
#pragma unroll
      for (int i = 0; i < 4; ++i)
        af[i] = *(const bf16x8*)&khs[w * 64 + i * 16 + fr][ks * 32 + fk];
#pragma unroll
      for (int j = 0; j < 4; ++j)
        bf[j] = *(const bf16x8*)(vt + (size_t)(vb4 * 64 + j * 16 + fr) * Tt + ks * 32 + fk);
#pragma unroll
      for (int i = 0; i < 4; ++i)
#pragma unroll
        for (int j = 0; j < 4; ++j)
          acc[i][j] = __builtin_amdgcn_mfma_f32_16x16x32_bf16(af[i], bf[j], acc[i][j], 0, 0, 0);
    }
#pragma unroll
    for (int i = 0; i < 4; ++i)
#pragma unroll
      for (int j = 0; j < 4; ++j)
#pragma unroll
        for (int r = 0; r < 4; ++r)
          Sb[(size_t)task * (Kk * Vv) + (size_t)(w * 64 + i * 16 + fq * 4 + r) * Vv +
             vb4 * 64 + j * 16 + fr] = f2b(acc[i][j][r]);
  }
}

// ---------------- passR: sequential chunk recombine; 64k x 32v tiles (256 blocks) ----
__global__ __launch_bounds__(256) void passR_kernel(
    const unsigned short* __restrict__ Sb, const float* __restrict__ Dendb,
    unsigned short* __restrict__ S0Tb, float* __restrict__ state_out) {
  const int vt = blockIdx.x, kt = blockIdx.y, b = blockIdx.z;
  const int tid = threadIdx.x;
  const int kq = tid >> 2;
  const int vq = tid & 3;
  const int vr = tid >> 3;
  const int kqq = tid & 7;
  __shared__ __align__(16) unsigned short Ts[32][72];
  float st[8];
#pragma unroll
  for (int j = 0; j < 8; ++j) st[j] = 0.f;
  for (int c = 0; c < NC; ++c) {
    const int task = b * NC + c;
#pragma unroll
    for (int j = 0; j < 8; ++j) Ts[vq * 8 + j][kq] = f2b(st[j]);
    __syncthreads();
    {
      unsigned short* dst = S0Tb + (size_t)task * (Kk * Vv) +
                            (size_t)(vt * 32 + vr) * Kk + kt * 64 + kqq * 8;
      *(uint4*)dst = *(const uint4*)&Ts[vr][kqq * 8];
    }
    __syncthreads();
    const float d = Dendb[task * 256 + kt * 64 + kq];
    const unsigned short* sp = Sb + (size_t)task * (Kk * Vv) +
                               (size_t)(kt * 64 + kq) * Vv + vt * 32 + vq * 8;
    uint4 raw = *(const uint4*)sp;
    unsigned ws_[4] = {raw.x, raw.y, raw.z, raw.w};
#pragma unroll
    for (int e = 0; e < 4; ++e) {
      float lo = __uint_as_float(ws_[e] << 16);
      float hi = __uint_as_float(ws_[e] & 0xFFFF0000u);
      st[e * 2]     = d * st[e * 2] + lo;
      st[e * 2 + 1] = d * st[e * 2 + 1] + hi;
    }
  }
  float* so = state_out + (size_t)(b * Kk + kt * 64 + kq) * Vv + vt * 32 + vq * 8;
#pragma unroll
  for (int j = 0; j < 8; ++j) so[j] = st[j];
}

// ---------------- passO: per (b,c): att = q2*S0 + tril(A)*v ----------------
__global__ __launch_bounds__(256) void passO_kernel(
    const unsigned short* __restrict__ qab, const unsigned short* __restrict__ kab,
    const unsigned short* __restrict__ q2b, const float* __restrict__ LBb,
    const unsigned short* __restrict__ S0Tb, const unsigned short* __restrict__ vTb,
    unsigned short* __restrict__ attb) {
  const int c = blockIdx.x, b = blockIdx.y;
  const int task = b * NC + c;
  const int tid = threadIdx.x, lane = tid & 63, w = tid >> 6;
  const int fr = lane & 15, fq = lane >> 4, fk = fq * 8;
  __shared__ float LB_s[4][256];
  __shared__ float D_s[6][256];
  __shared__ __align__(16) unsigned short A_s[64][72];
  const size_t tbase = (size_t)task * (CC * Kk);
  for (int idx = tid; idx < 1024; idx += 256) LB_s[idx >> 8][idx & 255] = LBb[(size_t)task * 1024 + idx];
  for (int idx = tid; idx < 64 * 72 / 2; idx += 256) ((unsigned*)A_s)[idx] = 0;
  __syncthreads();
  {
    const int kk = tid;
#pragma unroll
    for (int pi = 0; pi < 6; ++pi) {
      const int I = (pi >= 3) ? 3 : (pi >= 1) ? 2 : 1;
      const int J = pi - (I * (I - 1)) / 2;
      D_s[pi][kk] = exp2f(LB_s[I][kk] - LB_s[J][kk]);
    }
  }
  __syncthreads();
  for (int p = w; p < 10; p += 4) {
    const int I = (p >= 6) ? 3 : (p >= 3) ? 2 : (p >= 1) ? 1 : 0;
    const int J = p - (I * (I + 1)) / 2;
    const int pidx = (I * (I - 1)) / 2 + J;
    f32x4 acc = {0.f, 0.f, 0.f, 0.f};
#pragma unroll
    for (int ks = 0; ks < 8; ++ks) {
      const int k0 = ks * 32 + fk;
      bf16x8 af = *(const bf16x8*)(qab + tbase + (size_t)(I * 16 + fr) * Kk + k0);
      if (I != J) {
#pragma unroll
        for (int e = 0; e < 8; ++e)
          af[e] = (__bf16)((float)af[e] * D_s[pidx][k0 + e]);
      }
      bf16x8 bf = *(const bf16x8*)(kab + tbase + (size_t)(J * 16 + fr) * Kk + k0);
      acc = __builtin_amdgcn_mfma_f32_16x16x32_bf16(af, bf, acc, 0, 0, 0);
    }
#pragma unroll
    for (int r = 0; r < 4; ++r) {
      const int ml = fq * 4 + r, nl = fr;
      bool keep = (I != J) || (nl <= ml);
      A_s[I * 16 + ml][J * 16 + nl] = keep ? f2b(acc[r]) : (unsigned short)0;
    }
  }
  __syncthreads();
  f32x4 acc2[4][4] = {};
  const unsigned short* q2t = q2b + tbase;
  const unsigned short* s0t = S0Tb + (size_t)task * (Kk * Vv);
  const unsigned short* vtp = vTb + (size_t)b * (Vv * Tt) + (size_t)c * CC;
  const int vbase = w * 64;
#pragma unroll
  for (int ks = 0; ks < 8; ++ks) {
    const int k0 = ks * 32 + fk;
    bf16x8 af[4], bf[4];
#pragma unroll
    for (int i = 0; i < 4; ++i) af[i] = *(const bf16x8*)(q2t + (size_t)(i * 16 + fr) * Kk + k0);
#pragma unroll
    for (int j = 0; j < 4; ++j) bf[j] = *(const bf16x8*)(s0t + (size_t)(vbase + j * 16 + fr) * Kk + k0);
#pragma unroll
    for (int i = 0; i < 4; ++i)
#pragma unroll
      for (int j = 0; j < 4; ++j)
        acc2[i][j] = __builtin_amdgcn_mfma_f32_16x16x32_bf16(af[i], bf[j], acc2[i][j], 0, 0, 0);
  }
#pragma unroll
  for (int ks = 0; ks < 2; ++ks) {
    const int s0 = ks * 32 + fk;
    bf16x8 af[4], bf[4];
#pragma unroll
    for (int i = 0; i < 4; ++i) af[i] = *(const bf16x8*)&A_s[i * 16 + fr][s0];
#pragma unroll
    for (int j = 0; j < 4; ++j) bf[j] = *(const bf16x8*)(vtp + (size_t)(vbase + j * 16 + fr) * Tt + s0);
#pragma unroll
    for (int i = 0; i < 4; ++i)
#pragma unroll
      for (int j = 0; j < 4; ++j)
        acc2[i][j] = __builtin_amdgcn_mfma_f32_16x16x32_bf16(af[i], bf[j], acc2[i][j], 0, 0, 0);
  }
#pragma unroll
  for (int i = 0; i < 4; ++i)
#pragma unroll
    for (int j = 0; j < 4; ++j)
#pragma unroll
      for (int r = 0; r < 4; ++r)
        attb[((size_t)b * Tt + c * CC + i * 16 + fq * 4 + r) * Vv + vbase + j * 16 + fr]
            = f2b(acc2[i][j][r]);
}

extern "C" void kernel_launch(void* const* d_in, const int* in_sizes, int n_in,
                              void* d_out, int out_size, void* d_ws, size_t ws_size,
                              hipStream_t stream) {
  const float* hs = (const float*)d_in[0];
  const float* Wq = (const float*)d_in[1];
  const float* bq = (const float*)d_in[2];
  const float* Wk = (const float*)d_in[3];
  const float* bk = (const float*)d_in[4];
  const float* Wv = (const float*)d_in[5];
  const float* bv = (const float*)d_in[6];
  const float* Wg = (const float*)d_in[7];
  const float* bg = (const float*)d_in[8];
  const float* Wo = (const float*)d_in[9];
  const float* bo = (const float*)d_in[10];

  float* out = (float*)d_out;
  float* state_out = out + (size_t)Bb * Tt * Oo;

  char* p = (char*)d_ws;
  auto alloc = [&](size_t bytes) {
    char* r = p;
    p += (bytes + 255) & ~(size_t)255;
    return r;
  };
  unsigned short* hsb   = (unsigned short*)alloc((size_t)Bb * Tt * Hh * 2);   // 32MB
  unsigned short* WallT = (unsigned short*)alloc((size_t)1024 * Hh * 2);      // 2MB
  unsigned short* WoT   = (unsigned short*)alloc((size_t)Oo * Vv * 2);
  unsigned short* qb    = (unsigned short*)alloc((size_t)Bb * Tt * Kk * 2);   // 8MB each
  unsigned short* kb    = (unsigned short*)alloc((size_t)Bb * Tt * Kk * 2);
  unsigned short* lgb   = (unsigned short*)alloc((size_t)Bb * Tt * Kk * 2);   // f16
  unsigned short* vTb   = (unsigned short*)alloc((size_t)Bb * Vv * Tt * 2);
  unsigned short* attb  = (unsigned short*)alloc((size_t)Bb * Tt * Vv * 2);
  unsigned short* q2b   = (unsigned short*)alloc((size_t)Bb * Tt * Kk * 2);
  unsigned short* qab   = (unsigned short*)alloc((size_t)Bb * Tt * Kk * 2);
  unsigned short* kab   = (unsigned short*)alloc((size_t)Bb * Tt * Kk * 2);
  float*          LBb   = (float*)alloc((size_t)Bb * NC * 4 * Kk * 4);
  float*          Dendb = (float*)alloc((size_t)Bb * NC * Kk * 4);
  unsigned short* Sb    = (unsigned short*)alloc((size_t)Bb * NC * Kk * Vv * 2);  // 32MB
  unsigned short* S0Tb  = (unsigned short*)alloc((size_t)Bb * NC * Kk * Vv * 2);  // 32MB

  // 1) casts + weight transposes (concat projection weights into WallT rows)
  int n4 = Bb * Tt * Hh / 4;
  cast_bf16_kernel<<<(n4 + 255) / 256, 256, 0, stream>>>(hs, hsb, n4);
  transpose_cast_kernel<<<dim3(Hh / 32, Kk / 32), 256, 0, stream>>>(Wq, WallT + 0 * Kk * Hh, Hh, Kk);
  transpose_cast_kernel<<<dim3(Hh / 32, Kk / 32), 256, 0, stream>>>(Wk, WallT + 1 * Kk * Hh, Hh, Kk);
  transpose_cast_kernel<<<dim3(Hh / 32, Kk / 32), 256, 0, stream>>>(Wg, WallT + 2 * Kk * Hh, Hh, Kk);
  transpose_cast_kernel<<<dim3(Hh / 32, Kk / 32), 256, 0, stream>>>(Wv, WallT + 3 * Kk * Hh, Hh, Kk);
  transpose_cast_kernel<<<dim3(Vv / 32, Oo / 32), 256, 0, stream>>>(Wo, WoT, Vv, Oo);

  // 2) fused projections: persistent 2-m-tile blocks (L2-resident working set)
  gemm_proj_kernel<<<512, 256, 0, stream>>>(
      hsb, WallT, bq, bk, bg, bv, qb, kb, lgb, vTb, Hh);

  // 3) fused prep + per-chunk state GEMM
  prep_sgemm_kernel<<<dim3(NC, Bb), 256, 0, stream>>>(qb, kb, lgb, vTb, q2b, qab, kab,
                                                      LBb, Dendb, Sb);

  // 4) sequential chunk recombine -> S0T (pre-chunk states) + final state
  passR_kernel<<<dim3(Vv / 32, Kk / 64, Bb), 256, 0, stream>>>(Sb, Dendb, S0Tb, state_out);

  // 5) outputs: att = q2.S0 + tril(A).v
  passO_kernel<<<dim3(NC, Bb), 256, 0, stream>>>(qab, kab, q2b, LBb, S0Tb, vTb, attb);

  // 6) output projection: LDS-staged f32 epilogue (coalesced 512B rows)
  gemm_out_kernel<<<dim3(Oo / BN, (Bb * Tt) / BM), 256, 0, stream>>>(
      attb, WoT, bo, out, Bb * Tt, Oo, Vv);
}

// Round 13
// 223.519 us; speedup vs baseline: 1.3125x; 1.3125x over previous
//
#include <hip/hip_runtime.h>

// Problem dims (fixed by setup_inputs)
#define Bb 8
#define Tt 2048
#define Hh 1024
#define Kk 256
#define Vv 256
#define Oo 1024
#define CC 64   // chunk length
#define NC 32   // chunks per batch (Tt/CC)

typedef __attribute__((ext_vector_type(8))) __bf16 bf16x8;
typedef __attribute__((ext_vector_type(4))) float f32x4;

__device__ __forceinline__ unsigned short f2b(float f) {
  unsigned u = __float_as_uint(f);
  u = (u + 0x7FFFu + ((u >> 16) & 1u)) >> 16;
  return (unsigned short)u;
}
__device__ __forceinline__ float b2f(unsigned short u) {
  return __uint_as_float(((unsigned)u) << 16);
}
__device__ __forceinline__ void gload_lds16(const unsigned short* g, unsigned short* l) {
  __builtin_amdgcn_global_load_lds(
      (const __attribute__((address_space(1))) void*)g,
      (__attribute__((address_space(3))) void*)l, 16, 0, 0);
}

// ---------------- cast f32 -> bf16 (vectorized) ----------------
__global__ __launch_bounds__(256) void cast_bf16_kernel(const float* __restrict__ in,
                                                        unsigned short* __restrict__ out,
                                                        int n4) {
  int i = blockIdx.x * 256 + threadIdx.x;
  if (i >= n4) return;
  float4 v = ((const float4*)in)[i];
  ushort4 o;
  o.x = f2b(v.x); o.y = f2b(v.y); o.z = f2b(v.z); o.w = f2b(v.w);
  ((ushort4*)out)[i] = o;
}

// ---------------- transpose + cast: W (H x N) f32 -> WT (N x H) bf16 ----------------
__global__ __launch_bounds__(256) void transpose_cast_kernel(const float* __restrict__ W,
                                                             unsigned short* __restrict__ WT,
                                                             int H, int N) {
  __shared__ float tile[32][33];
  int h0 = blockIdx.x * 32, n0 = blockIdx.y * 32;
  int tx = threadIdx.x & 31, ty = threadIdx.x >> 5;
  for (int r = ty; r < 32; r += 8)
    tile[r][tx] = W[(size_t)(h0 + r) * N + n0 + tx];
  __syncthreads();
  for (int r = ty; r < 32; r += 8)
    WT[(size_t)(n0 + r) * H + h0 + tx] = f2b(tile[tx][r]);
}

// ---------------- GEMM: 128x128, BK=32 DOUBLE-BUFFERED + counted vmcnt, 4 blocks/CU --
// Per iter: STAGE(next tile -> other buf, 4 loads/wave) ; vmcnt(4)+s_barrier (current
// tile's loads, issued LAST iter, are the oldest -> already landed; the 4 just-issued
// stay in flight ACROSS the barrier) ; ds_read + 16 MFMA ; raw s_barrier.
// Race-free: end-of-iter barrier separates all reads of buf X from next stage into X.
// MODE 0: proj epilogue (LDS-staged coalesced; v written transposed). MODE 1: f32+bias.
#define BM 128
#define BN 128
#define BK 32

template <int MODE>
__global__ __launch_bounds__(256, 4) void gemm_mf_kernel(
    const unsigned short* __restrict__ A, const unsigned short* __restrict__ Bt,
    const float* __restrict__ b0p, const float* __restrict__ b1p,
    const float* __restrict__ b2p, const float* __restrict__ b3p,
    float* __restrict__ Cf,
    unsigned short* __restrict__ O0, unsigned short* __restrict__ O1,
    unsigned short* __restrict__ O2, unsigned short* __restrict__ O3,
    int M, int N, int K) {
  // 32 KiB pool: As[2][128*32] + Bs[2][128*32]; reused by MODE-0 epilogue stage.
  __shared__ __align__(16) unsigned short shbuf[16384];
  unsigned short* As = shbuf;          // 2 bufs x 4096
  unsigned short* Bs = shbuf + 8192;   // 2 bufs x 4096
  const int tid = threadIdx.x;
  const int lane = tid & 63, wid = tid >> 6;        // 4 waves
  const int wm = wid >> 1, wn = wid & 1;            // 2x2; wave = 64x64 out
  // XCD-local mapping: XCD (lin&7) owns contiguous m-panels; n fastest (round-10).
  const int lin = blockIdx.x + blockIdx.y * gridDim.x;
  const int xcd = lin & 7;
  const int jj = lin >> 3;
  const int mpg = gridDim.y >> 3;
  const int m0 = (xcd * mpg + jj / gridDim.x) * BM;
  const int n0 = (jj % gridDim.x) * BN;
  const int fr = lane & 15, fq = lane >> 4;
  // staging: per gload a wave writes 16 rows x 64B (1 KiB). Lane l -> row +(l>>2),
  // LDS 16B-chunk (l&3); global source chunk = (l&3) ^ ((l>>2)&3)  [row base %16==0].
  const int srl = lane >> 2;
  const int scs = ((lane & 3) ^ (srl & 3)) * 8;
  const unsigned short* gaBase = A + (size_t)(m0 + srl) * K + scs;
  const unsigned short* gbBase = Bt + (size_t)(n0 + srl) * K + scs;
  const int nt = K / BK;

#define STAGE(buf, tt)                                                         \
  {                                                                            \
    _Pragma("unroll") for (int inst = 0; inst < 2; ++inst) {                   \
      const int rb = wid * 32 + inst * 16;                                     \
      gload_lds16(gaBase + (size_t)rb * K + (size_t)(tt) * BK,                 \
                  &As[(buf) * 4096 + rb * BK]);                                \
      gload_lds16(gbBase + (size_t)rb * K + (size_t)(tt) * BK,                 \
                  &Bs[(buf) * 4096 + rb * BK]);                                \
    }                                                                          \
  }

  f32x4 acc[4][4] = {};
  STAGE(0, 0);
  int cur = 0;
  for (int t = 0; t < nt; ++t) {
    if (t + 1 < nt) {
      STAGE(cur ^ 1, t + 1);  // 4 loads in flight across the barriers below
      asm volatile("s_waitcnt vmcnt(4)\n\ts_barrier" ::: "memory");
    } else {
      asm volatile("s_waitcnt vmcnt(0)\n\ts_barrier" ::: "memory");
    }
    {
      bf16x8 af[4], bfv[4];
#pragma unroll
      for (int j = 0; j < 4; ++j) {
        const int R = wn * 64 + j * 16 + fr;
        const int ch = fq ^ (R & 3);
        bfv[j] = *(const bf16x8*)&Bs[cur * 4096 + R * BK + ch * 8];
      }
#pragma unroll
      for (int i = 0; i < 4; ++i) {
        const int R = wm * 64 + i * 16 + fr;
        const int ch = fq ^ (R & 3);
        af[i] = *(const bf16x8*)&As[cur * 4096 + R * BK + ch * 8];
      }
#pragma unroll
      for (int i = 0; i < 4; ++i)
#pragma unroll
        for (int j = 0; j < 4; ++j)
          acc[i][j] = __builtin_amdgcn_mfma_f32_16x16x32_bf16(af[i], bfv[j], acc[i][j], 0, 0, 0);
    }
    asm volatile("s_barrier" ::: "memory");  // reads done before next stage into buf
    cur ^= 1;
  }
#undef STAGE

  if (MODE == 1) {
#pragma unroll
    for (int j = 0; j < 4; ++j) {
      const int n = n0 + wn * 64 + j * 16 + fr;
      const float bv = b0p[n];
#pragma unroll
      for (int i = 0; i < 4; ++i) {
        const int mb = m0 + wm * 64 + i * 16 + fq * 4;
#pragma unroll
        for (int r = 0; r < 4; ++r)
          Cf[(size_t)(mb + r) * N + n] = acc[i][j][r] + bv;
      }
    }
  } else {
    // LDS-staged epilogue (round-10): coalesced 256B rows; v-panel staged transposed
    const int sel = n0 >> 8;
    const float* bp = sel == 0 ? b0p : sel == 1 ? b1p : sel == 2 ? b2p : b3p;
#pragma unroll
    for (int j = 0; j < 4; ++j) {
      const int ncol = wn * 64 + j * 16 + fr;       // [0,128)
      const float bv = bp[(n0 & 255) + ncol];
#pragma unroll
      for (int i = 0; i < 4; ++i) {
#pragma unroll
        for (int r = 0; r < 4; ++r) {
          const int ml = wm * 64 + i * 16 + fq * 4 + r;
          const float x = acc[i][j][r] + bv;
          unsigned short us;
          if (sel == 0) {
            us = f2b(x);
          } else if (sel == 1) {
            us = f2b(1.f / (1.f + expf(-x)));
          } else if (sel == 2) {
            float e = exp2f(-x * 1.44269504f);
            float lg = -log2f(1.f + e);
            _Float16 hv = (_Float16)lg;
            __builtin_memcpy(&us, &hv, 2);
          } else {
            us = f2b(x);
          }
          if (sel == 3) {  // transposed: row=v(ncol), col=t(ml)
            const int cm = (ml >> 3) ^ (ncol & 15);
            shbuf[ncol * 128 + cm * 8 + (ml & 7)] = us;
          } else {
            const int cn = (ncol >> 3) ^ (ml & 15);
            shbuf[ml * 128 + cn * 8 + (ncol & 7)] = us;
          }
        }
      }
    }
    __syncthreads();
    const int row = tid >> 1;
    const int half = tid & 1;
    if (sel == 3) {
      unsigned short* dst = O3 + ((size_t)(m0 >> 11) * Vv + (n0 & 255) + row) * Tt +
                            (m0 & 2047) + half * 64;
#pragma unroll
      for (int ic = 0; ic < 8; ++ic) {
        const int chunk = half * 8 + ic;
        const int sc = chunk ^ (row & 15);
        *(uint4*)(dst + ic * 8) = *(const uint4*)&shbuf[row * 128 + sc * 8];
      }
    } else {
      unsigned short* Op = sel == 0 ? O0 : sel == 1 ? O1 : O2;
      unsigned short* dst = Op + (size_t)(m0 + row) * 256 + (n0 & 255) + half * 64;
#pragma unroll
      for (int ic = 0; ic < 8; ++ic) {
        const int chunk = half * 8 + ic;
        const int sc = chunk ^ (row & 15);
        *(uint4*)(dst + ic * 8) = *(const uint4*)&shbuf[row * 128 + sc * 8];
      }
    }
  }
}

// ---------------- fused prep+sgemm: per (b,c) task ----------------
__global__ __launch_bounds__(256) void prep_sgemm_kernel(
    const unsigned short* __restrict__ qb, const unsigned short* __restrict__ kb,
    const unsigned short* __restrict__ lgb, const unsigned short* __restrict__ vTb,
    unsigned short* __restrict__ q2b, unsigned short* __restrict__ qab,
    unsigned short* __restrict__ kab,
    float* __restrict__ LBb, float* __restrict__ Dendb,
    unsigned short* __restrict__ Sb) {
  __shared__ __align__(16) unsigned short khs[256][72];
  const int c = blockIdx.x, b = blockIdx.y;
  const int k = threadIdx.x;
  const int task = b * NC + c;
  const size_t rowbase = ((size_t)b * Tt + (size_t)c * CC) * Kk + k;
  float Ls = 0.f;
  float LBr[4];
#pragma unroll
  for (int gq = 0; gq < 4; ++gq) {
    LBr[gq] = Ls;
#pragma unroll
    for (int tt = 0; tt < 16; ++tt) {
      int t = gq * 16 + tt;
      _Float16 hv;
      __builtin_memcpy(&hv, &lgb[rowbase + (size_t)t * Kk], 2);
      Ls += (float)hv;
    }
  }
  const float Lend = Ls;
#pragma unroll
  for (int gq = 0; gq < 4; ++gq) LBb[(size_t)task * 1024 + gq * 256 + k] = LBr[gq];
  Dendb[task * 256 + k] = exp2f(Lend);
  float L = 0.f;
#pragma unroll
  for (int gq = 0; gq < 4; ++gq) {
    const float LBc = LBr[gq];
    unsigned kw[8];
#pragma unroll
    for (int tt = 0; tt < 16; ++tt) {
      int t = gq * 16 + tt;
      size_t off = rowbase + (size_t)t * Kk;
      _Float16 hv;
      __builtin_memcpy(&hv, &lgb[off], 2);
      L += (float)hv;
      float qv = b2f(qb[off]);
      float kv = b2f(kb[off]);
      q2b[off] = f2b(qv * exp2f(L));
      qab[off] = f2b(qv * exp2f(L - LBc));
      kab[off] = f2b(kv * exp2f(LBc - L));
      unsigned short kh = f2b(kv * exp2f(Lend - L));
      if (tt & 1) kw[tt >> 1] |= ((unsigned)kh) << 16;
      else        kw[tt >> 1] = kh;
    }
    uint4 u0; u0.x = kw[0]; u0.y = kw[1]; u0.z = kw[2]; u0.w = kw[3];
    uint4 u1; u1.x = kw[4]; u1.y = kw[5]; u1.z = kw[6]; u1.w = kw[7];
    *(uint4*)&khs[k][gq * 16] = u0;
    *(uint4*)&khs[k][gq * 16 + 8] = u1;
  }
  __syncthreads();
  const int tid = threadIdx.x, lane = tid & 63, w = tid >> 6;
  const int fr = lane & 15, fq = lane >> 4, fk = fq * 8;
  const unsigned short* vt = vTb + (size_t)b * (Vv * Tt) + (size_t)c * CC;
  for (int vb4 = 0; vb4 < 4; ++vb4) {
    f32x4 acc[4][4] = {};
#pragma unroll
    for (int ks = 0; ks < 2; ++ks) {
      bf16x8 af[4], bf[4];
#pragma unroll
      for (int i = 0; i < 4; ++i)
        af[i] = *(const bf16x8*)&khs[w * 64 + i * 16 + fr][ks * 32 + fk];
#pragma unroll
      for (int j = 0; j < 4; ++j)
        bf[j] = *(const bf16x8*)(vt + (size_t)(vb4 * 64 + j * 16 + fr) * Tt + ks * 32 + fk);
#pragma unroll
      for (int i = 0; i < 4; ++i)
#pragma unroll
        for (int j = 0; j < 4; ++j)
          acc[i][j] = __builtin_amdgcn_mfma_f32_16x16x32_bf16(af[i], bf[j], acc[i][j], 0, 0, 0);
    }
#pragma unroll
    for (int i = 0; i < 4; ++i)
#pragma unroll
      for (int j = 0; j < 4; ++j)
#pragma unroll
        for (int r = 0; r < 4; ++r)
          Sb[(size_t)task * (Kk * Vv) + (size_t)(w * 64 + i * 16 + fq * 4 + r) * Vv +
             vb4 * 64 + j * 16 + fr] = f2b(acc[i][j][r]);
  }
}

// ---------------- passR: sequential chunk recombine; 64k x 32v tiles (256 blocks) ----
__global__ __launch_bounds__(256) void passR_kernel(
    const unsigned short* __restrict__ Sb, const float* __restrict__ Dendb,
    unsigned short* __restrict__ S0Tb, float* __restrict__ state_out) {
  const int vt = blockIdx.x, kt = blockIdx.y, b = blockIdx.z;
  const int tid = threadIdx.x;
  const int kq = tid >> 2;
  const int vq = tid & 3;
  const int vr = tid >> 3;
  const int kqq = tid & 7;
  __shared__ __align__(16) unsigned short Ts[32][72];
  float st[8];
#pragma unroll
  for (int j = 0; j < 8; ++j) st[j] = 0.f;
  for (int c = 0; c < NC; ++c) {
    const int task = b * NC + c;
#pragma unroll
    for (int j = 0; j < 8; ++j) Ts[vq * 8 + j][kq] = f2b(st[j]);
    __syncthreads();
    {
      unsigned short* dst = S0Tb + (size_t)task * (Kk * Vv) +
                            (size_t)(vt * 32 + vr) * Kk + kt * 64 + kqq * 8;
      *(uint4*)dst = *(const uint4*)&Ts[vr][kqq * 8];
    }
    __syncthreads();
    const float d = Dendb[task * 256 + kt * 64 + kq];
    const unsigned short* sp = Sb + (size_t)task * (Kk * Vv) +
                               (size_t)(kt * 64 + kq) * Vv + vt * 32 + vq * 8;
    uint4 raw = *(const uint4*)sp;
    unsigned ws_[4] = {raw.x, raw.y, raw.z, raw.w};
#pragma unroll
    for (int e = 0; e < 4; ++e) {
      float lo = __uint_as_float(ws_[e] << 16);
      float hi = __uint_as_float(ws_[e] & 0xFFFF0000u);
      st[e * 2]     = d * st[e * 2] + lo;
      st[e * 2 + 1] = d * st[e * 2 + 1] + hi;
    }
  }
  float* so = state_out + (size_t)(b * Kk + kt * 64 + kq) * Vv + vt * 32 + vq * 8;
#pragma unroll
  for (int j = 0; j < 8; ++j) so[j] = st[j];
}

// ---------------- passO: per (b,c): att = q2*S0 + tril(A)*v ----------------
__global__ __launch_bounds__(256) void passO_kernel(
    const unsigned short* __restrict__ qab, const unsigned short* __restrict__ kab,
    const unsigned short* __restrict__ q2b, const float* __restrict__ LBb,
    const unsigned short* __restrict__ S0Tb, const unsigned short* __restrict__ vTb,
    unsigned short* __restrict__ attb) {
  const int c = blockIdx.x, b = blockIdx.y;
  const int task = b * NC + c;
  const int tid = threadIdx.x, lane = tid & 63, w = tid >> 6;
  const int fr = lane & 15, fq = lane >> 4, fk = fq * 8;
  __shared__ float LB_s[4][256];
  __shared__ float D_s[6][256];
  __shared__ __align__(16) unsigned short A_s[64][72];
  const size_t tbase = (size_t)task * (CC * Kk);
  for (int idx = tid; idx < 1024; idx += 256) LB_s[idx >> 8][idx & 255] = LBb[(size_t)task * 1024 + idx];
  for (int idx = tid; idx < 64 * 72 / 2; idx += 256) ((unsigned*)A_s)[idx] = 0;
  __syncthreads();
  {
    const int kk = tid;
#pragma unroll
    for (int pi = 0; pi < 6; ++pi) {
      const int I = (pi >= 3) ? 3 : (pi >= 1) ? 2 : 1;
      const int J = pi - (I * (I - 1)) / 2;
      D_s[pi][kk] = exp2f(LB_s[I][kk] - LB_s[J][kk]);
    }
  }
  __syncthreads();
  for (int p = w; p < 10; p += 4) {
    const int I = (p >= 6) ? 3 : (p >= 3) ? 2 : (p >= 1) ? 1 : 0;
    const int J = p - (I * (I + 1)) / 2;
    const int pidx = (I * (I - 1)) / 2 + J;
    f32x4 acc = {0.f, 0.f, 0.f, 0.f};
#pragma unroll
    for (int ks = 0; ks < 8; ++ks) {
      const int k0 = ks * 32 + fk;
      bf16x8 af = *(const bf16x8*)(qab + tbase + (size_t)(I * 16 + fr) * Kk + k0);
      if (I != J) {
#pragma unroll
        for (int e = 0; e < 8; ++e)
          af[e] = (__bf16)((float)af[e] * D_s[pidx][k0 + e]);
      }
      bf16x8 bf = *(const bf16x8*)(kab + tbase + (size_t)(J * 16 + fr) * Kk + k0);
      acc = __builtin_amdgcn_mfma_f32_16x16x32_bf16(af, bf, acc, 0, 0, 0);
    }
#pragma unroll
    for (int r = 0; r < 4; ++r) {
      const int ml = fq * 4 + r, nl = fr;
      bool keep = (I != J) || (nl <= ml);
      A_s[I * 16 + ml][J * 16 + nl] = keep ? f2b(acc[r]) : (unsigned short)0;
    }
  }
  __syncthreads();
  f32x4 acc2[4][4] = {};
  const unsigned short* q2t = q2b + tbase;
  const unsigned short* s0t = S0Tb + (size_t)task * (Kk * Vv);
  const unsigned short* vtp = vTb + (size_t)b * (Vv * Tt) + (size_t)c * CC;
  const int vbase = w * 64;
#pragma unroll
  for (int ks = 0; ks < 8; ++ks) {
    const int k0 = ks * 32 + fk;
    bf16x8 af[4], bf[4];
#pragma unroll
    for (int i = 0; i < 4; ++i) af[i] = *(const bf16x8*)(q2t + (size_t)(i * 16 + fr) * Kk + k0);
#pragma unroll
    for (int j = 0; j < 4; ++j) bf[j] = *(const bf16x8*)(s0t + (size_t)(vbase + j * 16 + fr) * Kk + k0);
#pragma unroll
    for (int i = 0; i < 4; ++i)
#pragma unroll
      for (int j = 0; j < 4; ++j)
        acc2[i][j] = __builtin_amdgcn_mfma_f32_16x16x32_bf16(af[i], bf[j], acc2[i][j], 0, 0, 0);
  }
#pragma unroll
  for (int ks = 0; ks < 2; ++ks) {
    const int s0 = ks * 32 + fk;
    bf16x8 af[4], bf[4];
#pragma unroll
    for (int i = 0; i < 4; ++i) af[i] = *(const bf16x8*)&A_s[i * 16 + fr][s0];
#pragma unroll
    for (int j = 0; j < 4; ++j) bf[j] = *(const bf16x8*)(vtp + (size_t)(vbase + j * 16 + fr) * Tt + s0);
#pragma unroll
    for (int i = 0; i < 4; ++i)
#pragma unroll
      for (int j = 0; j < 4; ++j)
        acc2[i][j] = __builtin_amdgcn_mfma_f32_16x16x32_bf16(af[i], bf[j], acc2[i][j], 0, 0, 0);
  }
#pragma unroll
  for (int i = 0; i < 4; ++i)
#pragma unroll
    for (int j = 0; j < 4; ++j)
#pragma unroll
      for (int r = 0; r < 4; ++r)
        attb[((size_t)b * Tt + c * CC + i * 16 + fq * 4 + r) * Vv + vbase + j * 16 + fr]
            = f2b(acc2[i][j][r]);
}

extern "C" void kernel_launch(void* const* d_in, const int* in_sizes, int n_in,
                              void* d_out, int out_size, void* d_ws, size_t ws_size,
                              hipStream_t stream) {
  const float* hs = (const float*)d_in[0];
  const float* Wq = (const float*)d_in[1];
  const float* bq = (const float*)d_in[2];
  const float* Wk = (const float*)d_in[3];
  const float* bk = (const float*)d_in[4];
  const float* Wv = (const float*)d_in[5];
  const float* bv = (const float*)d_in[6];
  const float* Wg = (const float*)d_in[7];
  const float* bg = (const float*)d_in[8];
  const float* Wo = (const float*)d_in[9];
  const float* bo = (const float*)d_in[10];

  float* out = (float*)d_out;
  float* state_out = out + (size_t)Bb * Tt * Oo;

  char* p = (char*)d_ws;
  auto alloc = [&](size_t bytes) {
    char* r = p;
    p += (bytes + 255) & ~(size_t)255;
    return r;
  };
  unsigned short* hsb   = (unsigned short*)alloc((size_t)Bb * Tt * Hh * 2);   // 32MB
  unsigned short* WallT = (unsigned short*)alloc((size_t)1024 * Hh * 2);      // 2MB
  unsigned short* WoT   = (unsigned short*)alloc((size_t)Oo * Vv * 2);
  unsigned short* qb    = (unsigned short*)alloc((size_t)Bb * Tt * Kk * 2);   // 8MB each
  unsigned short* kb    = (unsigned short*)alloc((size_t)Bb * Tt * Kk * 2);
  unsigned short* lgb   = (unsigned short*)alloc((size_t)Bb * Tt * Kk * 2);   // f16
  unsigned short* vTb   = (unsigned short*)alloc((size_t)Bb * Vv * Tt * 2);
  unsigned short* attb  = (unsigned short*)alloc((size_t)Bb * Tt * Vv * 2);
  unsigned short* q2b   = (unsigned short*)alloc((size_t)Bb * Tt * Kk * 2);
  unsigned short* qab   = (unsigned short*)alloc((size_t)Bb * Tt * Kk * 2);
  unsigned short* kab   = (unsigned short*)alloc((size_t)Bb * Tt * Kk * 2);
  float*          LBb   = (float*)alloc((size_t)Bb * NC * 4 * Kk * 4);
  float*          Dendb = (float*)alloc((size_t)Bb * NC * Kk * 4);
  unsigned short* Sb    = (unsigned short*)alloc((size_t)Bb * NC * Kk * Vv * 2);  // 32MB
  unsigned short* S0Tb  = (unsigned short*)alloc((size_t)Bb * NC * Kk * Vv * 2);  // 32MB

  // 1) casts + weight transposes (concat projection weights into WallT rows)
  int n4 = Bb * Tt * Hh / 4;
  cast_bf16_kernel<<<(n4 + 255) / 256, 256, 0, stream>>>(hs, hsb, n4);
  transpose_cast_kernel<<<dim3(Hh / 32, Kk / 32), 256, 0, stream>>>(Wq, WallT + 0 * Kk * Hh, Hh, Kk);
  transpose_cast_kernel<<<dim3(Hh / 32, Kk / 32), 256, 0, stream>>>(Wk, WallT + 1 * Kk * Hh, Hh, Kk);
  transpose_cast_kernel<<<dim3(Hh / 32, Kk / 32), 256, 0, stream>>>(Wg, WallT + 2 * Kk * Hh, Hh, Kk);
  transpose_cast_kernel<<<dim3(Hh / 32, Kk / 32), 256, 0, stream>>>(Wv, WallT + 3 * Kk * Hh, Hh, Kk);
  transpose_cast_kernel<<<dim3(Vv / 32, Oo / 32), 256, 0, stream>>>(Wo, WoT, Vv, Oo);

  // 2) fused projections: 128^2 tiles, dbuf+counted vmcnt, 4 blocks/CU
  gemm_mf_kernel<0><<<dim3(1024 / BN, (Bb * Tt) / BM), 256, 0, stream>>>(
      hsb, WallT, bq, bk, bg, bv, nullptr, qb, kb, lgb, vTb, Bb * Tt, 1024, Hh);

  // 3) fused prep + per-chunk state GEMM
  prep_sgemm_kernel<<<dim3(NC, Bb), 256, 0, stream>>>(qb, kb, lgb, vTb, q2b, qab, kab,
                                                      LBb, Dendb, Sb);

  // 4) sequential chunk recombine -> S0T (pre-chunk states) + final state
  passR_kernel<<<dim3(Vv / 32, Kk / 64, Bb), 256, 0, stream>>>(Sb, Dendb, S0Tb, state_out);

  // 5) outputs: att = q2.S0 + tril(A).v
  passO_kernel<<<dim3(NC, Bb), 256, 0, stream>>>(qab, kab, q2b, LBb, S0Tb, vTb, attb);

  // 6) output projection: dbuf+counted vmcnt, f32 out
  gemm_mf_kernel<1><<<dim3(Oo / BN, (Bb * Tt) / BM), 256, 0, stream>>>(
      attb, WoT, bo, nullptr, nullptr, nullptr, out, nullptr, nullptr, nullptr, nullptr,
      Bb * Tt, Oo, Vv);
}

// Round 14
// 222.820 us; speedup vs baseline: 1.3166x; 1.0031x over previous
//
#include <hip/hip_runtime.h>

// Problem dims (fixed by setup_inputs)
#define Bb 8
#define Tt 2048
#define Hh 1024
#define Kk 256
#define Vv 256
#define Oo 1024
#define CC 64   // chunk length
#define NC 32   // chunks per batch (Tt/CC)

typedef __attribute__((ext_vector_type(8))) __bf16 bf16x8;
typedef __attribute__((ext_vector_type(4))) float f32x4;

__device__ __forceinline__ unsigned short f2b(float f) {
  unsigned u = __float_as_uint(f);
  u = (u + 0x7FFFu + ((u >> 16) & 1u)) >> 16;
  return (unsigned short)u;
}
__device__ __forceinline__ float b2f(unsigned short u) {
  return __uint_as_float(((unsigned)u) << 16);
}
__device__ __forceinline__ void gload_lds16(const unsigned short* g, unsigned short* l) {
  __builtin_amdgcn_global_load_lds(
      (const __attribute__((address_space(1))) void*)g,
      (__attribute__((address_space(3))) void*)l, 16, 0, 0);
}

// ---------------- cast f32 -> bf16 (vectorized) ----------------
__global__ __launch_bounds__(256) void cast_bf16_kernel(const float* __restrict__ in,
                                                        unsigned short* __restrict__ out,
                                                        int n4) {
  int i = blockIdx.x * 256 + threadIdx.x;
  if (i >= n4) return;
  float4 v = ((const float4*)in)[i];
  ushort4 o;
  o.x = f2b(v.x); o.y = f2b(v.y); o.z = f2b(v.z); o.w = f2b(v.w);
  ((ushort4*)out)[i] = o;
}

// ---------------- transpose + cast: W (H x N) f32 -> WT (N x H) bf16 ----------------
__global__ __launch_bounds__(256) void transpose_cast_kernel(const float* __restrict__ W,
                                                             unsigned short* __restrict__ WT,
                                                             int H, int N) {
  __shared__ float tile[32][33];
  int h0 = blockIdx.x * 32, n0 = blockIdx.y * 32;
  int tx = threadIdx.x & 31, ty = threadIdx.x >> 5;
  for (int r = ty; r < 32; r += 8)
    tile[r][tx] = W[(size_t)(h0 + r) * N + n0 + tx];
  __syncthreads();
  for (int r = ty; r < 32; r += 8)
    WT[(size_t)(n0 + r) * H + h0 + tx] = f2b(tile[tx][r]);
}

// ---------------- proj GEMM: 128x128, BK=64, 4 waves, swizzled LDS (round-10 best) ----
#define BM 128
#define BN 128
#define BK 64

__global__ __launch_bounds__(256, 4) void gemm_proj_kernel(
    const unsigned short* __restrict__ A, const unsigned short* __restrict__ Bt,
    const float* __restrict__ b0p, const float* __restrict__ b1p,
    const float* __restrict__ b2p, const float* __restrict__ b3p,
    unsigned short* __restrict__ O0, unsigned short* __restrict__ O1,
    unsigned short* __restrict__ O2, unsigned short* __restrict__ O3,
    int M, int N, int K) {
  // One 32 KiB LDS pool: As/Bs during the K loop, reused as the epilogue stage tile.
  __shared__ __align__(16) unsigned short shbuf[16384];
  unsigned short* As = shbuf;          // 128*64
  unsigned short* Bs = shbuf + 8192;   // 128*64
  const int tid = threadIdx.x;
  const int lane = tid & 63, wid = tid >> 6;        // 4 waves
  const int wm = wid >> 1, wn = wid & 1;            // 2x2 wave grid; wave = 64x64 out
  // XCD-local mapping: XCD (lin&7) owns contiguous m-panels; n iterated fastest.
  const int lin = blockIdx.x + blockIdx.y * gridDim.x;
  const int xcd = lin & 7;
  const int jj = lin >> 3;
  const int mpg = gridDim.y >> 3;
  const int m0 = (xcd * mpg + jj / gridDim.x) * BM;
  const int n0 = (jj % gridDim.x) * BN;
  const int fr = lane & 15, fq = lane >> 4;
  // staging: per gload a wave writes 8 rows x 128B. Lane l -> row +(l>>3),
  // LDS 16B-chunk (l&7); global source chunk = (l&7) ^ (l>>3).
  const int srl = lane >> 3;
  const int scs = ((lane & 7) ^ srl) * 8;
  const unsigned short* gaBase = A + (size_t)(m0 + srl) * K + scs;
  const unsigned short* gbBase = Bt + (size_t)(n0 + srl) * K + scs;

  f32x4 acc[4][4] = {};
  const int nt = K / BK;
  for (int t = 0; t < nt; ++t) {
    const int k0 = t * BK;
    __syncthreads();  // previous iter's LDS reads done
#pragma unroll
    for (int inst = 0; inst < 4; ++inst) {
      const int rb = wid * 32 + inst * 8;
      gload_lds16(gaBase + (size_t)rb * K + k0, &As[rb * BK]);
      gload_lds16(gbBase + (size_t)rb * K + k0, &Bs[rb * BK]);
    }
    __syncthreads();  // staged data visible (drain hidden by co-resident blocks)
#pragma unroll
    for (int ks = 0; ks < 2; ++ks) {
      bf16x8 af[4], bfv[4];
#pragma unroll
      for (int j = 0; j < 4; ++j) {
        const int R = wn * 64 + j * 16 + fr;
        const int ch = ((ks << 2) | fq) ^ (fr & 7);
        bfv[j] = *(const bf16x8*)&Bs[R * BK + ch * 8];
      }
#pragma unroll
      for (int i = 0; i < 4; ++i) {
        const int R = wm * 64 + i * 16 + fr;
        const int ch = ((ks << 2) | fq) ^ (fr & 7);
        af[i] = *(const bf16x8*)&As[R * BK + ch * 8];
      }
#pragma unroll
      for (int i = 0; i < 4; ++i)
#pragma unroll
        for (int j = 0; j < 4; ++j)
          acc[i][j] = __builtin_amdgcn_mfma_f32_16x16x32_bf16(af[i], bfv[j], acc[i][j], 0, 0, 0);
    }
  }
  // LDS-staged epilogue: coalesced 256B rows; v-panel staged transposed -> vT direct
  __syncthreads();
  const int sel = n0 >> 8;
  const float* bp = sel == 0 ? b0p : sel == 1 ? b1p : sel == 2 ? b2p : b3p;
#pragma unroll
  for (int j = 0; j < 4; ++j) {
    const int ncol = wn * 64 + j * 16 + fr;       // [0,128)
    const float bv = bp[(n0 & 255) + ncol];
#pragma unroll
    for (int i = 0; i < 4; ++i) {
#pragma unroll
      for (int r = 0; r < 4; ++r) {
        const int ml = wm * 64 + i * 16 + fq * 4 + r;
        const float x = acc[i][j][r] + bv;
        unsigned short us;
        if (sel == 0) {
          us = f2b(x);
        } else if (sel == 1) {
          us = f2b(1.f / (1.f + expf(-x)));
        } else if (sel == 2) {
          float e = exp2f(-x * 1.44269504f);
          float lg = -log2f(1.f + e);
          _Float16 hv = (_Float16)lg;
          __builtin_memcpy(&us, &hv, 2);
        } else {
          us = f2b(x);
        }
        if (sel == 3) {  // stage transposed: row=v(ncol), col=t(ml)
          const int cm = (ml >> 3) ^ (ncol & 15);
          shbuf[ncol * 128 + cm * 8 + (ml & 7)] = us;
        } else {
          const int cn = (ncol >> 3) ^ (ml & 15);
          shbuf[ml * 128 + cn * 8 + (ncol & 7)] = us;
        }
      }
    }
  }
  __syncthreads();
  const int row = tid >> 1;
  const int half = tid & 1;
  if (sel == 3) {
    unsigned short* dst = O3 + ((size_t)(m0 >> 11) * Vv + (n0 & 255) + row) * Tt +
                          (m0 & 2047) + half * 64;
#pragma unroll
    for (int ic = 0; ic < 8; ++ic) {
      const int chunk = half * 8 + ic;
      const int sc = chunk ^ (row & 15);
      *(uint4*)(dst + ic * 8) = *(const uint4*)&shbuf[row * 128 + sc * 8];
    }
  } else {
    unsigned short* Op = sel == 0 ? O0 : sel == 1 ? O1 : O2;
    unsigned short* dst = Op + (size_t)(m0 + row) * 256 + (n0 & 255) + half * 64;
#pragma unroll
    for (int ic = 0; ic < 8; ++ic) {
      const int chunk = half * 8 + ic;
      const int sc = chunk ^ (row & 15);
      *(uint4*)(dst + ic * 8) = *(const uint4*)&shbuf[row * 128 + sc * 8];
    }
  }
}

// ---------------- fused prep+sgemm: per (b,c) task ----------------
__global__ __launch_bounds__(256) void prep_sgemm_kernel(
    const unsigned short* __restrict__ qb, const unsigned short* __restrict__ kb,
    const unsigned short* __restrict__ lgb, const unsigned short* __restrict__ vTb,
    unsigned short* __restrict__ q2b, unsigned short* __restrict__ qab,
    unsigned short* __restrict__ kab,
    float* __restrict__ LBb, float* __restrict__ Dendb,
    unsigned short* __restrict__ Sb) {
  __shared__ __align__(16) unsigned short khs[256][72];
  const int c = blockIdx.x, b = blockIdx.y;
  const int k = threadIdx.x;
  const int task = b * NC + c;
  const size_t rowbase = ((size_t)b * Tt + (size_t)c * CC) * Kk + k;
  float Ls = 0.f;
  float LBr[4];
#pragma unroll
  for (int gq = 0; gq < 4; ++gq) {
    LBr[gq] = Ls;
#pragma unroll
    for (int tt = 0; tt < 16; ++tt) {
      int t = gq * 16 + tt;
      _Float16 hv;
      __builtin_memcpy(&hv, &lgb[rowbase + (size_t)t * Kk], 2);
      Ls += (float)hv;
    }
  }
  const float Lend = Ls;
#pragma unroll
  for (int gq = 0; gq < 4; ++gq) LBb[(size_t)task * 1024 + gq * 256 + k] = LBr[gq];
  Dendb[task * 256 + k] = exp2f(Lend);
  float L = 0.f;
#pragma unroll
  for (int gq = 0; gq < 4; ++gq) {
    const float LBc = LBr[gq];
    unsigned kw[8];
#pragma unroll
    for (int tt = 0; tt < 16; ++tt) {
      int t = gq * 16 + tt;
      size_t off = rowbase + (size_t)t * Kk;
      _Float16 hv;
      __builtin_memcpy(&hv, &lgb[off], 2);
      L += (float)hv;
      float qv = b2f(qb[off]);
      float kv = b2f(kb[off]);
      q2b[off] = f2b(qv * exp2f(L));
      qab[off] = f2b(qv * exp2f(L - LBc));
      kab[off] = f2b(kv * exp2f(LBc - L));
      unsigned short kh = f2b(kv * exp2f(Lend - L));
      if (tt & 1) kw[tt >> 1] |= ((unsigned)kh) << 16;
      else        kw[tt >> 1] = kh;
    }
    uint4 u0; u0.x = kw[0]; u0.y = kw[1]; u0.z = kw[2]; u0.w = kw[3];
    uint4 u1; u1.x = kw[4]; u1.y = kw[5]; u1.z = kw[6]; u1.w = kw[7];
    *(uint4*)&khs[k][gq * 16] = u0;
    *(uint4*)&khs[k][gq * 16 + 8] = u1;
  }
  __syncthreads();
  const int tid = threadIdx.x, lane = tid & 63, w = tid >> 6;
  const int fr = lane & 15, fq = lane >> 4, fk = fq * 8;
  const unsigned short* vt = vTb + (size_t)b * (Vv * Tt) + (size_t)c * CC;
  for (int vb4 = 0; vb4 < 4; ++vb4) {
    f32x4 acc[4][4] = {};
#pragma unroll
    for (int ks = 0; ks < 2; ++ks) {
      bf16x8 af[4], bf[4];
#pragma unroll
      for (int i = 0; i < 4; ++i)
        af[i] = *(const bf16x8*)&khs[w * 64 + i * 16 + fr][ks * 32 + fk];
#pragma unroll
      for (int j = 0; j < 4; ++j)
        bf[j] = *(const bf16x8*)(vt + (size_t)(vb4 * 64 + j * 16 + fr) * Tt + ks * 32 + fk);
#pragma unroll
      for (int i = 0; i < 4; ++i)
#pragma unroll
        for (int j = 0; j < 4; ++j)
          acc[i][j] = __builtin_amdgcn_mfma_f32_16x16x32_bf16(af[i], bf[j], acc[i][j], 0, 0, 0);
    }
#pragma unroll
    for (int i = 0; i < 4; ++i)
#pragma unroll
      for (int j = 0; j < 4; ++j)
#pragma unroll
        for (int r = 0; r < 4; ++r)
          Sb[(size_t)task * (Kk * Vv) + (size_t)(w * 64 + i * 16 + fq * 4 + r) * Vv +
             vb4 * 64 + j * 16 + fr] = f2b(acc[i][j][r]);
  }
}

// ---------------- passR: sequential chunk recombine; 64k x 32v tiles (256 blocks) ----
__global__ __launch_bounds__(256) void passR_kernel(
    const unsigned short* __restrict__ Sb, const float* __restrict__ Dendb,
    unsigned short* __restrict__ S0Tb, float* __restrict__ state_out) {
  const int vt = blockIdx.x, kt = blockIdx.y, b = blockIdx.z;
  const int tid = threadIdx.x;
  const int kq = tid >> 2;
  const int vq = tid & 3;
  const int vr = tid >> 3;
  const int kqq = tid & 7;
  __shared__ __align__(16) unsigned short Ts[32][72];
  float st[8];
#pragma unroll
  for (int j = 0; j < 8; ++j) st[j] = 0.f;
  for (int c = 0; c < NC; ++c) {
    const int task = b * NC + c;
#pragma unroll
    for (int j = 0; j < 8; ++j) Ts[vq * 8 + j][kq] = f2b(st[j]);
    __syncthreads();
    {
      unsigned short* dst = S0Tb + (size_t)task * (Kk * Vv) +
                            (size_t)(vt * 32 + vr) * Kk + kt * 64 + kqq * 8;
      *(uint4*)dst = *(const uint4*)&Ts[vr][kqq * 8];
    }
    __syncthreads();
    const float d = Dendb[task * 256 + kt * 64 + kq];
    const unsigned short* sp = Sb + (size_t)task * (Kk * Vv) +
                               (size_t)(kt * 64 + kq) * Vv + vt * 32 + vq * 8;
    uint4 raw = *(const uint4*)sp;
    unsigned ws_[4] = {raw.x, raw.y, raw.z, raw.w};
#pragma unroll
    for (int e = 0; e < 4; ++e) {
      float lo = __uint_as_float(ws_[e] << 16);
      float hi = __uint_as_float(ws_[e] & 0xFFFF0000u);
      st[e * 2]     = d * st[e * 2] + lo;
      st[e * 2 + 1] = d * st[e * 2 + 1] + hi;
    }
  }
  float* so = state_out + (size_t)(b * Kk + kt * 64 + kq) * Vv + vt * 32 + vq * 8;
#pragma unroll
  for (int j = 0; j < 8; ++j) so[j] = st[j];
}

// ---------------- passO (FUSED): att = q2*S0 + tril(A)*v, then out = att*Wo + bo ----
__global__ __launch_bounds__(256) void passO_kernel(
    const unsigned short* __restrict__ qab, const unsigned short* __restrict__ kab,
    const unsigned short* __restrict__ q2b, const float* __restrict__ LBb,
    const unsigned short* __restrict__ S0Tb, const unsigned short* __restrict__ vTb,
    const unsigned short* __restrict__ WoT, const float* __restrict__ bo,
    float* __restrict__ outp) {
  const int c = blockIdx.x, b = blockIdx.y;
  const int task = b * NC + c;
  const int tid = threadIdx.x, lane = tid & 63, w = tid >> 6;
  const int fr = lane & 15, fq = lane >> 4, fk = fq * 8;
  __shared__ float LB_s[4][256];
  __shared__ float D_s[6][256];
  __shared__ __align__(16) unsigned short A_s[64][72];
  __shared__ __align__(16) unsigned short att_s[64][264];  // att tile, padded
  const size_t tbase = (size_t)task * (CC * Kk);
  for (int idx = tid; idx < 1024; idx += 256) LB_s[idx >> 8][idx & 255] = LBb[(size_t)task * 1024 + idx];
  for (int idx = tid; idx < 64 * 72 / 2; idx += 256) ((unsigned*)A_s)[idx] = 0;
  __syncthreads();
  {
    const int kk = tid;
#pragma unroll
    for (int pi = 0; pi < 6; ++pi) {
      const int I = (pi >= 3) ? 3 : (pi >= 1) ? 2 : 1;
      const int J = pi - (I * (I - 1)) / 2;
      D_s[pi][kk] = exp2f(LB_s[I][kk] - LB_s[J][kk]);
    }
  }
  __syncthreads();
  for (int p = w; p < 10; p += 4) {
    const int I = (p >= 6) ? 3 : (p >= 3) ? 2 : (p >= 1) ? 1 : 0;
    const int J = p - (I * (I + 1)) / 2;
    const int pidx = (I * (I - 1)) / 2 + J;
    f32x4 acc = {0.f, 0.f, 0.f, 0.f};
#pragma unroll
    for (int ks = 0; ks < 8; ++ks) {
      const int k0 = ks * 32 + fk;
      bf16x8 af = *(const bf16x8*)(qab + tbase + (size_t)(I * 16 + fr) * Kk + k0);
      if (I != J) {
#pragma unroll
        for (int e = 0; e < 8; ++e)
          af[e] = (__bf16)((float)af[e] * D_s[pidx][k0 + e]);
      }
      bf16x8 bf = *(const bf16x8*)(kab + tbase + (size_t)(J * 16 + fr) * Kk + k0);
      acc = __builtin_amdgcn_mfma_f32_16x16x32_bf16(af, bf, acc, 0, 0, 0);
    }
#pragma unroll
    for (int r = 0; r < 4; ++r) {
      const int ml = fq * 4 + r, nl = fr;
      bool keep = (I != J) || (nl <= ml);
      A_s[I * 16 + ml][J * 16 + nl] = keep ? f2b(acc[r]) : (unsigned short)0;
    }
  }
  __syncthreads();
  f32x4 acc2[4][4] = {};
  const unsigned short* q2t = q2b + tbase;
  const unsigned short* s0t = S0Tb + (size_t)task * (Kk * Vv);
  const unsigned short* vtp = vTb + (size_t)b * (Vv * Tt) + (size_t)c * CC;
  const int vbase = w * 64;
#pragma unroll
  for (int ks = 0; ks < 8; ++ks) {
    const int k0 = ks * 32 + fk;
    bf16x8 af[4], bf[4];
#pragma unroll
    for (int i = 0; i < 4; ++i) af[i] = *(const bf16x8*)(q2t + (size_t)(i * 16 + fr) * Kk + k0);
#pragma unroll
    for (int j = 0; j < 4; ++j) bf[j] = *(const bf16x8*)(s0t + (size_t)(vbase + j * 16 + fr) * Kk + k0);
#pragma unroll
    for (int i = 0; i < 4; ++i)
#pragma unroll
      for (int j = 0; j < 4; ++j)
        acc2[i][j] = __builtin_amdgcn_mfma_f32_16x16x32_bf16(af[i], bf[j], acc2[i][j], 0, 0, 0);
  }
#pragma unroll
  for (int ks = 0; ks < 2; ++ks) {
    const int s0 = ks * 32 + fk;
    bf16x8 af[4], bf[4];
#pragma unroll
    for (int i = 0; i < 4; ++i) af[i] = *(const bf16x8*)&A_s[i * 16 + fr][s0];
#pragma unroll
    for (int j = 0; j < 4; ++j) bf[j] = *(const bf16x8*)(vtp + (size_t)(vbase + j * 16 + fr) * Tt + s0);
#pragma unroll
    for (int i = 0; i < 4; ++i)
#pragma unroll
      for (int j = 0; j < 4; ++j)
        acc2[i][j] = __builtin_amdgcn_mfma_f32_16x16x32_bf16(af[i], bf[j], acc2[i][j], 0, 0, 0);
  }
  // stage att tile (bf16) into LDS: att_s[t_local][v], wave w owns cols [w*64, w*64+64)
#pragma unroll
  for (int i = 0; i < 4; ++i)
#pragma unroll
    for (int j = 0; j < 4; ++j)
#pragma unroll
      for (int r = 0; r < 4; ++r)
        att_s[i * 16 + fq * 4 + r][vbase + j * 16 + fr] = f2b(acc2[i][j][r]);
  __syncthreads();
  // fused output projection: wave w covers o in [w*256, (w+1)*256), 4 chunks of 64.
  // out[t][o] = sum_v att[t][v] * WoT[o][v] + bo[o]
  const size_t orow = (size_t)b * Tt + (size_t)c * CC;
  for (int cc = 0; cc < 4; ++cc) {
    const int o0 = w * 256 + cc * 64;
    f32x4 acc3[4][4] = {};
#pragma unroll
    for (int ks = 0; ks < 8; ++ks) {
      const int k0 = ks * 32 + fk;
      bf16x8 af[4], bf[4];
#pragma unroll
      for (int i = 0; i < 4; ++i)
        af[i] = *(const bf16x8*)&att_s[i * 16 + fr][k0];
#pragma unroll
      for (int j = 0; j < 4; ++j)
        bf[j] = *(const bf16x8*)(WoT + (size_t)(o0 + j * 16 + fr) * Vv + k0);
#pragma unroll
      for (int i = 0; i < 4; ++i)
#pragma unroll
        for (int j = 0; j < 4; ++j)
          acc3[i][j] = __builtin_amdgcn_mfma_f32_16x16x32_bf16(af[i], bf[j], acc3[i][j], 0, 0, 0);
    }
#pragma unroll
    for (int j = 0; j < 4; ++j) {
      const int o = o0 + j * 16 + fr;
      const float bv = bo[o];
#pragma unroll
      for (int i = 0; i < 4; ++i) {
#pragma unroll
        for (int r = 0; r < 4; ++r)
          outp[(orow + i * 16 + fq * 4 + r) * Oo + o] = acc3[i][j][r] + bv;
      }
    }
  }
}

extern "C" void kernel_launch(void* const* d_in, const int* in_sizes, int n_in,
                              void* d_out, int out_size, void* d_ws, size_t ws_size,
                              hipStream_t stream) {
  const float* hs = (const float*)d_in[0];
  const float* Wq = (const float*)d_in[1];
  const float* bq = (const float*)d_in[2];
  const float* Wk = (const float*)d_in[3];
  const float* bk = (const float*)d_in[4];
  const float* Wv = (const float*)d_in[5];
  const float* bv = (const float*)d_in[6];
  const float* Wg = (const float*)d_in[7];
  const float* bg = (const float*)d_in[8];
  const float* Wo = (const float*)d_in[9];
  const float* bo = (const float*)d_in[10];

  float* out = (float*)d_out;
  float* state_out = out + (size_t)Bb * Tt * Oo;

  char* p = (char*)d_ws;
  auto alloc = [&](size_t bytes) {
    char* r = p;
    p += (bytes + 255) & ~(size_t)255;
    return r;
  };
  unsigned short* hsb   = (unsigned short*)alloc((size_t)Bb * Tt * Hh * 2);   // 32MB
  unsigned short* WallT = (unsigned short*)alloc((size_t)1024 * Hh * 2);      // 2MB
  unsigned short* WoT   = (unsigned short*)alloc((size_t)Oo * Vv * 2);
  unsigned short* qb    = (unsigned short*)alloc((size_t)Bb * Tt * Kk * 2);   // 8MB each
  unsigned short* kb    = (unsigned short*)alloc((size_t)Bb * Tt * Kk * 2);
  unsigned short* lgb   = (unsigned short*)alloc((size_t)Bb * Tt * Kk * 2);   // f16
  unsigned short* vTb   = (unsigned short*)alloc((size_t)Bb * Vv * Tt * 2);
  unsigned short* q2b   = (unsigned short*)alloc((size_t)Bb * Tt * Kk * 2);
  unsigned short* qab   = (unsigned short*)alloc((size_t)Bb * Tt * Kk * 2);
  unsigned short* kab   = (unsigned short*)alloc((size_t)Bb * Tt * Kk * 2);
  float*          LBb   = (float*)alloc((size_t)Bb * NC * 4 * Kk * 4);
  float*          Dendb = (float*)alloc((size_t)Bb * NC * Kk * 4);
  unsigned short* Sb    = (unsigned short*)alloc((size_t)Bb * NC * Kk * Vv * 2);  // 32MB
  unsigned short* S0Tb  = (unsigned short*)alloc((size_t)Bb * NC * Kk * Vv * 2);  // 32MB

  // 1) casts + weight transposes (concat projection weights into WallT rows)
  int n4 = Bb * Tt * Hh / 4;
  cast_bf16_kernel<<<(n4 + 255) / 256, 256, 0, stream>>>(hs, hsb, n4);
  transpose_cast_kernel<<<dim3(Hh / 32, Kk / 32), 256, 0, stream>>>(Wq, WallT + 0 * Kk * Hh, Hh, Kk);
  transpose_cast_kernel<<<dim3(Hh / 32, Kk / 32), 256, 0, stream>>>(Wk, WallT + 1 * Kk * Hh, Hh, Kk);
  transpose_cast_kernel<<<dim3(Hh / 32, Kk / 32), 256, 0, stream>>>(Wg, WallT + 2 * Kk * Hh, Hh, Kk);
  transpose_cast_kernel<<<dim3(Hh / 32, Kk / 32), 256, 0, stream>>>(Wv, WallT + 3 * Kk * Hh, Hh, Kk);
  transpose_cast_kernel<<<dim3(Vv / 32, Oo / 32), 256, 0, stream>>>(Wo, WoT, Vv, Oo);

  // 2) fused projections: 128^2 tiles (round-10 structure); v written transposed to vT
  gemm_proj_kernel<<<dim3(1024 / BN, (Bb * Tt) / BM), 256, 0, stream>>>(
      hsb, WallT, bq, bk, bg, bv, qb, kb, lgb, vTb, Bb * Tt, 1024, Hh);

  // 3) fused prep + per-chunk state GEMM
  prep_sgemm_kernel<<<dim3(NC, Bb), 256, 0, stream>>>(qb, kb, lgb, vTb, q2b, qab, kab,
                                                      LBb, Dendb, Sb);

  // 4) sequential chunk recombine -> S0T (pre-chunk states) + final state
  passR_kernel<<<dim3(Vv / 32, Kk / 64, Bb), 256, 0, stream>>>(Sb, Dendb, S0Tb, state_out);

  // 5) outputs: att = q2.S0 + tril(A).v, FUSED with out = att.Wo + bo (writes d_out)
  passO_kernel<<<dim3(NC, Bb), 256, 0, stream>>>(qab, kab, q2b, LBb, S0Tb, vTb,
                                                 WoT, bo, out);
}